// Round 2
// baseline (105.067 us; speedup 1.0000x reference)
//
#include <hip/hip_runtime.h>
#include <math.h>

#define KSZ   17
#define PADR  8
#define FDIM  100
#define ODIM  180
#define HTOT  512
#define WTOT  512
#define TILE  16
#define LDSW  48          // row stride 48: bank = (16*ty+tx)%32 -> exact 2-way (free)
#define TEMPERATURE 20.0f
#define THRESHOLD   55.0f

typedef float f32x4 __attribute__((ext_vector_type(4)));
typedef f32x4 uf32x4 __attribute__((aligned(4)));   // truthful 4-B alignment

// ---- order-preserving float<->uint encoding for atomic min/max ----
__device__ __forceinline__ unsigned int fenc(float f) {
    unsigned int u = __float_as_uint(f);
    return (u & 0x80000000u) ? ~u : (u | 0x80000000u);
}
__device__ __forceinline__ float fdec(unsigned int k) {
    unsigned int u = (k & 0x80000000u) ? (k ^ 0x80000000u) : ~k;
    return __uint_as_float(u);
}

__global__ __launch_bounds__(256) void filter_main(
    const float* __restrict__ x,
    const int*   __restrict__ freq,
    const int*   __restrict__ orient,
    const float* __restrict__ fb,
    float*       __restrict__ y,
    unsigned int* __restrict__ mm)
{
    __shared__ float tile[2 * TILE][LDSW];   // 32 x 48 floats = 6144 B

    const int bx = blockIdx.x, by = blockIdx.y;
    const int tid = threadIdx.x;
    const int tx = tid & (TILE - 1);
    const int ty = tid >> 4;

    const int h0 = by * TILE - PADR;
    const int w0 = bx * TILE - PADR;

    const int h = by * TILE + ty;
    const int w = bx * TILE + tx;
    const int pid = h * WTOT + w;

    // issue index loads before staging so they overlap
    int f0 = freq[pid] - 1;
    int o0 = orient[pid] - 1;

    // cooperative load of 32x32 region with zero padding outside the image
    for (int i = tid; i < 32 * 32; i += 256) {
        const int r = i >> 5, c = i & 31;
        const int gh = h0 + r, gw = w0 + c;
        float v = 0.f;
        if (gh >= 0 && gh < HTOT && gw >= 0 && gw < WTOT)
            v = x[gh * WTOT + gw];
        tile[r][c] = v;
    }

    f0 = f0 < 0 ? 0 : (f0 > FDIM - 1 ? FDIM - 1 : f0);
    o0 = o0 < 0 ? 0 : (o0 > ODIM - 1 ? ODIM - 1 : o0);
    const float* __restrict__ kf = fb + (size_t)(f0 * ODIM + o0) * (KSZ * KSZ);
    const uf32x4* __restrict__ kf4 = reinterpret_cast<const uf32x4*>(kf);

    __syncthreads();

    // flat-unrolled dot product: 72 x float4 + 1 scalar, 4 acc chains
    float a0 = 0.f, a1 = 0.f, a2 = 0.f, a3 = 0.f;
    #pragma unroll
    for (int j = 0; j < 72; ++j) {
        const f32x4 f = kf4[j];
        const int e0 = 4 * j;
        a0 = fmaf(f.x, tile[ty + (e0    ) / 17][tx + (e0    ) % 17], a0);
        a1 = fmaf(f.y, tile[ty + (e0 + 1) / 17][tx + (e0 + 1) % 17], a1);
        a2 = fmaf(f.z, tile[ty + (e0 + 2) / 17][tx + (e0 + 2) % 17], a2);
        a3 = fmaf(f.w, tile[ty + (e0 + 3) / 17][tx + (e0 + 3) % 17], a3);
    }
    float acc = ((a0 + a1) + (a2 + a3)) + kf[288] * tile[ty + 16][tx + 16];

    y[pid] = acc;

    // ---- block min/max reduce, then one atomic pair per block ----
    float mn = acc, mx = acc;
    #pragma unroll
    for (int off = 32; off > 0; off >>= 1) {
        mn = fminf(mn, __shfl_down(mn, off, 64));
        mx = fmaxf(mx, __shfl_down(mx, off, 64));
    }
    __shared__ float smn[4], smx[4];
    const int wid = tid >> 6, lane = tid & 63;
    if (lane == 0) { smn[wid] = mn; smx[wid] = mx; }
    __syncthreads();
    if (tid == 0) {
        float bmn = smn[0], bmx = smx[0];
        #pragma unroll
        for (int i = 1; i < 4; ++i) {
            bmn = fminf(bmn, smn[i]);
            bmx = fmaxf(bmx, smx[i]);
        }
        atomicMin(&mm[0], fenc(bmn));
        atomicMax(&mm[1], fenc(bmx));
    }
}

__global__ __launch_bounds__(256) void filter_final(
    float* __restrict__ y,
    const unsigned int* __restrict__ mm)
{
    const int i = blockIdx.x * 256 + threadIdx.x;
    const float ymin = fdec(mm[0]);
    const float ymax = fdec(mm[1]);
    const float rng  = fmaxf(ymax - ymin, 1e-8f);

    const float v  = y[i];
    const float o1 = 100.f * (v - ymin) / rng;                     // in [0,100]
    const float s  = 100.f / (1.f + expf(-(TEMPERATURE * (o1 * 0.01f - THRESHOLD * 0.01f))));

    // analytic post-sigmoid extrema: o1 hits exactly 0 and 100 at argmin/argmax
    const float smin = 100.f / (1.f + expf( 11.f));   // 100*sigmoid(-11)
    const float smax = 100.f / (1.f + expf(-9.f));    // 100*sigmoid(+9)
    const float srng = fmaxf(smax - smin, 1e-8f);

    y[i] = 100.f * (s - smin) / srng;
}

extern "C" void kernel_launch(void* const* d_in, const int* in_sizes, int n_in,
                              void* d_out, int out_size, void* d_ws, size_t ws_size,
                              hipStream_t stream) {
    const float* x      = (const float*)d_in[0];
    const int*   freq   = (const int*)d_in[1];
    const int*   orient = (const int*)d_in[2];
    const float* fb     = (const float*)d_in[3];
    float*       out    = (float*)d_out;           // doubles as y scratch
    unsigned int* mm    = (unsigned int*)d_ws;     // [0]=enc(min), [1]=enc(max)

    hipMemsetAsync(mm, 0xFF, 4, stream);
    hipMemsetAsync((char*)d_ws + 4, 0x00, 4, stream);

    dim3 grid(WTOT / TILE, HTOT / TILE);           // 32 x 32 blocks
    filter_main<<<grid, 256, 0, stream>>>(x, freq, orient, fb, out, mm);

    filter_final<<<(HTOT * WTOT) / 256, 256, 0, stream>>>(out, mm);
}

// Round 3
// 72.855 us; speedup vs baseline: 1.4421x; 1.4421x over previous
//
#include <hip/hip_runtime.h>
#include <math.h>

#define KSZ   17
#define PADR  8
#define FDIM  100
#define ODIM  180
#define HTOT  512
#define WTOT  512
#define TILE  16
#define LDSW  48
#define TEMPERATURE 20.0f
#define THRESHOLD   55.0f

// ---- order-preserving float<->uint encoding for atomic min/max ----
__device__ __forceinline__ unsigned int fenc(float f) {
    unsigned int u = __float_as_uint(f);
    return (u & 0x80000000u) ? ~u : (u | 0x80000000u);
}
__device__ __forceinline__ float fdec(unsigned int k) {
    unsigned int u = (k & 0x80000000u) ? (k ^ 0x80000000u) : ~k;
    return __uint_as_float(u);
}

__global__ __launch_bounds__(256) void filter_main(
    const float* __restrict__ x,
    const int*   __restrict__ freq,
    const int*   __restrict__ orient,
    const float* __restrict__ fb,
    float*       __restrict__ y,
    unsigned int* __restrict__ mm)
{
    __shared__ float tile[2 * TILE][LDSW];   // 32 x 48 floats
    __shared__ int   sidx[256];              // per-pixel filter index
    __shared__ float sacc[256];              // per-pixel correlation result

    const int bx = blockIdx.x, by = blockIdx.y;
    const int tid = threadIdx.x;
    const int px = tid & 15;                 // this thread's OWN pixel (staging)
    const int py = tid >> 4;

    const int h = by * TILE + py;
    const int w = bx * TILE + px;
    const int pid = h * WTOT + w;

    // per-pixel clamped filter index -> LDS
    int f0 = freq[pid] - 1;
    int o0 = orient[pid] - 1;
    f0 = f0 < 0 ? 0 : (f0 > FDIM - 1 ? FDIM - 1 : f0);
    o0 = o0 < 0 ? 0 : (o0 > ODIM - 1 ? ODIM - 1 : o0);
    sidx[tid] = f0 * ODIM + o0;

    // stage 32x32 input region (zero-padded at image borders)
    const int h0 = by * TILE - PADR;
    const int w0 = bx * TILE - PADR;
    for (int i = tid; i < 32 * 32; i += 256) {
        const int r = i >> 5, c = i & 31;
        const int gh = h0 + r, gw = w0 + c;
        float v = 0.f;
        if (gh >= 0 && gh < HTOT && gw >= 0 && gw < WTOT)
            v = x[gh * WTOT + gw];
        tile[r][c] = v;
    }
    __syncthreads();

    // ---- cooperative correlation: 16 lanes per pixel ----
    const int l  = tid & 15;                 // lane within quarter-wave
    const int qw = tid >> 4;                 // quarter-wave id = pixel column

    // per-lane patch offsets for rounds j=0..17 (element e = 16j + l)
    int offs[18];
    #pragma unroll
    for (int j = 0; j < 18; ++j) {
        const int e = j * 16 + l;
        offs[j] = (e / 17) * LDSW + (e % 17);
    }

    float mn =  3.4e38f, mx = -3.4e38f;

    for (int it = 0; it < 16; ++it) {
        const int p = it * 16 + qw;                          // pixel (row=it, col=qw)
        const float* __restrict__ kf   = fb + (size_t)sidx[p] * 289;
        const float* __restrict__ base = &tile[it][qw];      // patch top-left

        // 18 coalesced rounds (16 consecutive floats per quarter-wave each),
        // two accumulator chains for ILP
        float a0 = 0.f, a1 = 0.f;
        #pragma unroll
        for (int j = 0; j < 18; j += 2) {
            a0 = fmaf(kf[(j    ) * 16 + l], base[offs[j    ]], a0);
            a1 = fmaf(kf[(j + 1) * 16 + l], base[offs[j + 1]], a1);
        }
        float acc = a0 + a1;
        if (l == 0) acc = fmaf(kf[288], base[16 * LDSW + 16], acc);  // e = 288 tail

        // butterfly sum over the 16-lane group -> all 16 lanes hold the total
        #pragma unroll
        for (int off = 8; off; off >>= 1)
            acc += __shfl_xor(acc, off, 64);

        if (l == 0) sacc[p] = acc;
        mn = fminf(mn, acc);                 // every lane saw its group's sum
        mx = fmaxf(mx, acc);
    }
    __syncthreads();

    // coalesced y store
    y[pid] = sacc[tid];

    // ---- block min/max reduce (each lane covers its quarter-wave's 16 pixels;
    //      union over the block's 256 lanes = all 256 pixels) ----
    #pragma unroll
    for (int off = 32; off > 0; off >>= 1) {
        mn = fminf(mn, __shfl_down(mn, off, 64));
        mx = fmaxf(mx, __shfl_down(mx, off, 64));
    }
    __shared__ float smn[4], smx[4];
    const int wid = tid >> 6, lane = tid & 63;
    if (lane == 0) { smn[wid] = mn; smx[wid] = mx; }
    __syncthreads();
    if (tid == 0) {
        float bmn = smn[0], bmx = smx[0];
        #pragma unroll
        for (int i = 1; i < 4; ++i) {
            bmn = fminf(bmn, smn[i]);
            bmx = fmaxf(bmx, smx[i]);
        }
        atomicMin(&mm[0], fenc(bmn));
        atomicMax(&mm[1], fenc(bmx));
    }
}

__global__ __launch_bounds__(256) void filter_final(
    float* __restrict__ y,
    const unsigned int* __restrict__ mm)
{
    const int i = blockIdx.x * 256 + threadIdx.x;
    const float ymin = fdec(mm[0]);
    const float ymax = fdec(mm[1]);
    const float rng  = fmaxf(ymax - ymin, 1e-8f);

    const float v  = y[i];
    const float o1 = 100.f * (v - ymin) / rng;                     // in [0,100]
    const float s  = 100.f / (1.f + expf(-(TEMPERATURE * (o1 * 0.01f - THRESHOLD * 0.01f))));

    // analytic post-sigmoid extrema: o1 hits exactly 0 and 100 at argmin/argmax
    const float smin = 100.f / (1.f + expf( 11.f));   // 100*sigmoid(-11)
    const float smax = 100.f / (1.f + expf(-9.f));    // 100*sigmoid(+9)
    const float srng = fmaxf(smax - smin, 1e-8f);

    y[i] = 100.f * (s - smin) / srng;
}

extern "C" void kernel_launch(void* const* d_in, const int* in_sizes, int n_in,
                              void* d_out, int out_size, void* d_ws, size_t ws_size,
                              hipStream_t stream) {
    const float* x      = (const float*)d_in[0];
    const int*   freq   = (const int*)d_in[1];
    const int*   orient = (const int*)d_in[2];
    const float* fb     = (const float*)d_in[3];
    float*       out    = (float*)d_out;           // doubles as y scratch
    unsigned int* mm    = (unsigned int*)d_ws;     // [0]=enc(min), [1]=enc(max)

    hipMemsetAsync(mm, 0xFF, 4, stream);
    hipMemsetAsync((char*)d_ws + 4, 0x00, 4, stream);

    dim3 grid(WTOT / TILE, HTOT / TILE);           // 32 x 32 blocks
    filter_main<<<grid, 256, 0, stream>>>(x, freq, orient, fb, out, mm);

    filter_final<<<(HTOT * WTOT) / 256, 256, 0, stream>>>(out, mm);
}